// Round 7
// baseline (200.525 us; speedup 1.0000x reference)
//
#include <hip/hip_runtime.h>
#include <math.h>

#define B_   32
#define T_   8192
#define RNN_ 1024
#define ENC_ 512
#define ATT_ 128
#define LOC_ 32
#define K_   31
#define PAD_ 15

__device__ __forceinline__ float fast_tanh(float x) {
    x = fminf(15.f, fmaxf(-15.f, x));
    float e = __expf(2.f * x);
    return (e - 1.f) * __builtin_amdgcn_rcpf(e + 1.f);
}

__device__ __forceinline__ float fast_sigmoid(float x) {
    x = fminf(30.f, fmaxf(-30.f, x));
    float e = __expf(-x);
    return __builtin_amdgcn_rcpf(1.f + e);
}

// ---------------- Kernel A: fused weight-prep + query GEMV ----------------
__global__ __launch_bounds__(256) void k_prep_query(const float* __restrict__ queries,
                                                    const float* __restrict__ wq,
                                                    const float* __restrict__ wconv,
                                                    float* __restrict__ qout,
                                                    float* __restrict__ wT) {
    if (blockIdx.x == (B_ * ATT_) / 4) {
        for (int i = threadIdx.x; i < LOC_ * 2 * K_; i += blockDim.x) {
            int l = i / (2 * K_);
            int rem = i % (2 * K_);
            int c = rem / K_;
            int k = rem % K_;
            wT[k * (2 * LOC_) + c * LOC_ + l] = wconv[i];
        }
        return;
    }
    int w    = blockIdx.x * 4 + (threadIdx.x >> 6);
    int lane = threadIdx.x & 63;
    int b = w >> 7, a = w & 127;
    const float4* qrow = (const float4*)(queries + (size_t)b * RNN_);
    const float4* wrow = (const float4*)(wq + (size_t)a * RNN_);
    float acc = 0.f;
#pragma unroll
    for (int i = 0; i < 4; ++i) {
        float4 x = qrow[i * 64 + lane];
        float4 y = wrow[i * 64 + lane];
        acc += x.x * y.x + x.y * y.y + x.z * y.z + x.w * y.w;
    }
#pragma unroll
    for (int off = 32; off; off >>= 1) acc += __shfl_xor(acc, off);
    if (lane == 0) qout[b * ATT_ + a] = acc;
}

// ---------------- Kernel B: fused conv + 1x1 + tanh + score + sigmoid ------------
#define VT    2
#define BLK2  256
#define TILE2 (BLK2 * VT)  // 512 t's per block

__global__ __launch_bounds__(256) void k_score(
    const float* __restrict__ pm,          // [B,ATT,T]
    const float* __restrict__ prev,        // [B,T]
    const float* __restrict__ cum,         // [B,T]
    const unsigned char* __restrict__ masks,
    const float* __restrict__ qbuf,        // [B,ATT]
    const float* __restrict__ wT,          // [K][2][LOC]
    const float* __restrict__ w1,          // [ATT,LOC]
    const float* __restrict__ wsc,         // [ATT]
    float* __restrict__ pout)              // [B,T]
{
    __shared__ float sP[TILE2 + K_ - 1];
    __shared__ float sC[TILE2 + K_ - 1];
    int blk  = blockIdx.x;
    int b    = blk >> 4;
    int tile = blk & 15;
    int tbase = tile * TILE2;
    const float* prow = prev + (size_t)b * T_;
    const float* crow = cum + (size_t)b * T_;
    for (int i = threadIdx.x; i < TILE2 + K_ - 1; i += BLK2) {
        int g = tbase - PAD_ + i;
        bool ok = (g >= 0) && (g < T_);
        sP[i] = ok ? prow[g] : 0.f;
        sC[i] = ok ? crow[g] : 0.f;
    }
    __syncthreads();

    int lt = threadIdx.x * VT;
    int t0 = tbase + lt;

    float loc[LOC_][VT];
#pragma unroll
    for (int l = 0; l < LOC_; ++l)
#pragma unroll
        for (int j = 0; j < VT; ++j) loc[l][j] = 0.f;

    for (int k = 0; k < K_; ++k) {
        float pv[VT], cv[VT];
#pragma unroll
        for (int j = 0; j < VT; ++j) {
            pv[j] = sP[lt + k + j];
            cv[j] = sC[lt + k + j];
        }
        const float4* wp4 = (const float4*)(wT + k * (2 * LOC_));
        const float4* wc4 = (const float4*)(wT + k * (2 * LOC_) + LOC_);
#pragma unroll
        for (int lq = 0; lq < 8; ++lq) {
            float4 wp = wp4[lq];
            float4 wc = wc4[lq];
#pragma unroll
            for (int j = 0; j < VT; ++j) {
                loc[4 * lq + 0][j] = fmaf(wp.x, pv[j], fmaf(wc.x, cv[j], loc[4 * lq + 0][j]));
                loc[4 * lq + 1][j] = fmaf(wp.y, pv[j], fmaf(wc.y, cv[j], loc[4 * lq + 1][j]));
                loc[4 * lq + 2][j] = fmaf(wp.z, pv[j], fmaf(wc.z, cv[j], loc[4 * lq + 2][j]));
                loc[4 * lq + 3][j] = fmaf(wp.w, pv[j], fmaf(wc.w, cv[j], loc[4 * lq + 3][j]));
            }
        }
    }

    float score0 = 0.f, score1 = 0.f;
    const float* pmb = pm + (size_t)b * ATT_ * T_ + t0;
    const float* qb  = qbuf + b * ATT_;

    // Software-pipelined a-loop: prefetch next 8 pm float2s (registers are
    // free: occupancy is grid-limited at 2 blocks/CU regardless of VGPR).
    float2 pmbuf[8];
#pragma unroll
    for (int g = 0; g < 8; ++g)
        pmbuf[g] = *(const float2*)(pmb + (size_t)g * T_);

    for (int a0 = 0; a0 < ATT_; a0 += 8) {
        float2 cur[8];
#pragma unroll
        for (int g = 0; g < 8; ++g) cur[g] = pmbuf[g];
        if (a0 + 8 < ATT_) {
#pragma unroll
            for (int g = 0; g < 8; ++g)
                pmbuf[g] = *(const float2*)(pmb + (size_t)(a0 + 8 + g) * T_);
        }
#pragma unroll
        for (int g = 0; g < 8; ++g) {
            int a = a0 + g;
            float q   = qb[a];
            float wsa = wsc[a];
            const float4* w1a4 = (const float4*)(w1 + a * LOC_);
            float l20 = 0.f, l21 = 0.f;
#pragma unroll
            for (int lq = 0; lq < 8; ++lq) {
                float4 wv = w1a4[lq];
                l20 = fmaf(wv.x, loc[4 * lq + 0][0], l20);
                l21 = fmaf(wv.x, loc[4 * lq + 0][1], l21);
                l20 = fmaf(wv.y, loc[4 * lq + 1][0], l20);
                l21 = fmaf(wv.y, loc[4 * lq + 1][1], l21);
                l20 = fmaf(wv.z, loc[4 * lq + 2][0], l20);
                l21 = fmaf(wv.z, loc[4 * lq + 2][1], l21);
                l20 = fmaf(wv.w, loc[4 * lq + 3][0], l20);
                l21 = fmaf(wv.w, loc[4 * lq + 3][1], l21);
            }
            score0 += wsa * fast_tanh(q + cur[g].x + l20);
            score1 += wsa * fast_tanh(q + cur[g].y + l21);
        }
    }

    unsigned char m0 = masks[(size_t)b * T_ + t0];
    unsigned char m1 = masks[(size_t)b * T_ + t0 + 1];
    float s0 = m0 ? -3.0e38f : score0;
    float s1 = m1 ? -3.0e38f : score1;
    float2 out;
    out.x = fast_sigmoid(s0);
    out.y = fast_sigmoid(s1);
    *(float2*)(pout + (size_t)b * T_ + t0) = out;
}

// ---------------- Kernel C: alignments = prev*p + shift(prev*(1-p)) --------------
__global__ __launch_bounds__(256) void k_align(const float* __restrict__ p,
                                               const float* __restrict__ prev,
                                               float* __restrict__ align) {
    int idx = blockIdx.x * blockDim.x + threadIdx.x;
    int b  = idx / (T_ / 4);
    int t0 = (idx % (T_ / 4)) * 4;
    const float* pr = p + (size_t)b * T_;
    const float* vr = prev + (size_t)b * T_;
    float4 p4 = *(const float4*)(pr + t0);
    float4 v4 = *(const float4*)(vr + t0);
    float pm1 = (t0 > 0) ? pr[t0 - 1] : 0.f;
    float vm1 = (t0 > 0) ? vr[t0 - 1] : 0.f;
    float4 o;
    o.x = v4.x * p4.x + vm1 * (1.f - pm1);
    o.y = v4.y * p4.y + v4.x * (1.f - p4.x);
    o.z = v4.z * p4.z + v4.y * (1.f - p4.y);
    o.w = v4.w * p4.w + v4.z * (1.f - p4.z);
    *(float4*)(align + (size_t)b * T_ + t0) = o;
}

// ---------------- Kernel D: contexts[b,c] = sum_t align[b,t]*mem[b,c,t] ----------
// R3 best variant: one wave per (b,c) row, unroll 8, dual accumulators.
__global__ __launch_bounds__(256) void k_context(const float* __restrict__ mem,
                                                 const float* __restrict__ align,
                                                 float* __restrict__ ctx) {
    int w    = blockIdx.x * 4 + (threadIdx.x >> 6);
    int lane = threadIdx.x & 63;
    int b = w >> 9;   // /512
    int c = w & 511;
    const float4* mrow = (const float4*)(mem + ((size_t)b * ENC_ + c) * T_);
    const float4* arow = (const float4*)(align + (size_t)b * T_);
    float acc0 = 0.f, acc1 = 0.f;
#pragma unroll 8
    for (int i = 0; i < T_ / 256; ++i) {  // 32 iters, 16B/lane each
        float4 m = mrow[i * 64 + lane];
        float4 a = arow[i * 64 + lane];
        if (i & 1)
            acc1 += m.x * a.x + m.y * a.y + m.z * a.z + m.w * a.w;
        else
            acc0 += m.x * a.x + m.y * a.y + m.z * a.z + m.w * a.w;
    }
    float acc = acc0 + acc1;
#pragma unroll
    for (int off = 32; off; off >>= 1) acc += __shfl_xor(acc, off);
    if (lane == 0) ctx[b * ENC_ + c] = acc;
}

extern "C" void kernel_launch(void* const* d_in, const int* in_sizes, int n_in,
                              void* d_out, int out_size, void* d_ws, size_t ws_size,
                              hipStream_t stream) {
    const float* queries = (const float*)d_in[0];
    const float* memories = (const float*)d_in[1];
    const float* pm = (const float*)d_in[2];
    const float* prev = (const float*)d_in[3];
    const float* cum = (const float*)d_in[4];
    const unsigned char* masks = (const unsigned char*)d_in[5];
    const float* w_query = (const float*)d_in[6];
    const float* w_conv = (const float*)d_in[7];
    const float* w_1x1 = (const float*)d_in[8];
    const float* w_score = (const float*)d_in[9];

    float* out_ctx = (float*)d_out;                       // [B,ENC]
    float* out_align = (float*)d_out + (size_t)B_ * ENC_; // [B,T]

    float* ws_q = (float*)d_ws;                       // B*ATT
    float* ws_p = ws_q + B_ * ATT_;                   // B*T
    float* ws_wT = ws_p + (size_t)B_ * T_;            // K*2*LOC

    hipLaunchKernelGGL(k_prep_query, dim3((B_ * ATT_) / 4 + 1), dim3(256), 0, stream,
                       queries, w_query, w_conv, ws_q, ws_wT);
    hipLaunchKernelGGL(k_score, dim3(B_ * (T_ / TILE2)), dim3(BLK2), 0, stream,
                       pm, prev, cum, masks, ws_q, ws_wT, w_1x1, w_score, ws_p);
    hipLaunchKernelGGL(k_align, dim3((B_ * T_ / 4) / 256), dim3(256), 0, stream,
                       ws_p, prev, out_align);
    hipLaunchKernelGGL(k_context, dim3((B_ * ENC_) / 4), dim3(256), 0, stream,
                       memories, out_align, out_ctx);
}

// Round 8
// 167.762 us; speedup vs baseline: 1.1953x; 1.1953x over previous
//
#include <hip/hip_runtime.h>
#include <math.h>

#define B_   32
#define T_   8192
#define RNN_ 1024
#define ENC_ 512
#define ATT_ 128
#define LOC_ 32
#define K_   31
#define PAD_ 15

__device__ __forceinline__ float fast_tanh(float x) {
    x = fminf(15.f, fmaxf(-15.f, x));
    float e = __expf(2.f * x);
    return (e - 1.f) * __builtin_amdgcn_rcpf(e + 1.f);
}

__device__ __forceinline__ float fast_sigmoid(float x) {
    x = fminf(30.f, fmaxf(-30.f, x));
    float e = __expf(-x);
    return __builtin_amdgcn_rcpf(1.f + e);
}

// ---------------- Kernel A: fused weight-prep + query GEMV ----------------
__global__ __launch_bounds__(256) void k_prep_query(const float* __restrict__ queries,
                                                    const float* __restrict__ wq,
                                                    const float* __restrict__ wconv,
                                                    float* __restrict__ qout,
                                                    float* __restrict__ wT) {
    if (blockIdx.x == (B_ * ATT_) / 4) {
        for (int i = threadIdx.x; i < LOC_ * 2 * K_; i += blockDim.x) {
            int l = i / (2 * K_);
            int rem = i % (2 * K_);
            int c = rem / K_;
            int k = rem % K_;
            wT[k * (2 * LOC_) + c * LOC_ + l] = wconv[i];
        }
        return;
    }
    int w    = blockIdx.x * 4 + (threadIdx.x >> 6);
    int lane = threadIdx.x & 63;
    int b = w >> 7, a = w & 127;
    const float4* qrow = (const float4*)(queries + (size_t)b * RNN_);
    const float4* wrow = (const float4*)(wq + (size_t)a * RNN_);
    float acc = 0.f;
#pragma unroll
    for (int i = 0; i < 4; ++i) {
        float4 x = qrow[i * 64 + lane];
        float4 y = wrow[i * 64 + lane];
        acc += x.x * y.x + x.y * y.y + x.z * y.z + x.w * y.w;
    }
#pragma unroll
    for (int off = 32; off; off >>= 1) acc += __shfl_xor(acc, off);
    if (lane == 0) qout[b * ATT_ + a] = acc;
}

// ---------------- Kernel B: fused conv + 1x1 + tanh + score + sigmoid ------------
// VT=1: one t per thread, tile 256, grid 1024 blocks -> 4 waves/SIMD occupancy.
#define BLK2  256
#define TILE2 256

__global__ __launch_bounds__(256) void k_score(
    const float* __restrict__ pm,          // [B,ATT,T]
    const float* __restrict__ prev,        // [B,T]
    const float* __restrict__ cum,         // [B,T]
    const unsigned char* __restrict__ masks,
    const float* __restrict__ qbuf,        // [B,ATT]
    const float* __restrict__ wT,          // [K][2][LOC]
    const float* __restrict__ w1,          // [ATT,LOC]
    const float* __restrict__ wsc,         // [ATT]
    float* __restrict__ pout)              // [B,T]
{
    __shared__ float sP[TILE2 + K_ - 1];
    __shared__ float sC[TILE2 + K_ - 1];
    int blk  = blockIdx.x;
    int b    = blk >> 5;       // 32 tiles of 256 per row
    int tile = blk & 31;
    int tbase = tile * TILE2;
    const float* prow = prev + (size_t)b * T_;
    const float* crow = cum + (size_t)b * T_;
    for (int i = threadIdx.x; i < TILE2 + K_ - 1; i += BLK2) {
        int g = tbase - PAD_ + i;
        bool ok = (g >= 0) && (g < T_);
        sP[i] = ok ? prow[g] : 0.f;
        sC[i] = ok ? crow[g] : 0.f;
    }
    __syncthreads();

    int lt = threadIdx.x;
    int t0 = tbase + lt;

    float loc[LOC_];
#pragma unroll
    for (int l = 0; l < LOC_; ++l) loc[l] = 0.f;

    for (int k = 0; k < K_; ++k) {
        float pv = sP[lt + k];
        float cv = sC[lt + k];
        const float4* wp4 = (const float4*)(wT + k * (2 * LOC_));
        const float4* wc4 = (const float4*)(wT + k * (2 * LOC_) + LOC_);
#pragma unroll
        for (int lq = 0; lq < 8; ++lq) {
            float4 wp = wp4[lq];
            float4 wc = wc4[lq];
            loc[4 * lq + 0] = fmaf(wp.x, pv, fmaf(wc.x, cv, loc[4 * lq + 0]));
            loc[4 * lq + 1] = fmaf(wp.y, pv, fmaf(wc.y, cv, loc[4 * lq + 1]));
            loc[4 * lq + 2] = fmaf(wp.z, pv, fmaf(wc.z, cv, loc[4 * lq + 2]));
            loc[4 * lq + 3] = fmaf(wp.w, pv, fmaf(wc.w, cv, loc[4 * lq + 3]));
        }
    }

    float score = 0.f;
    const float* pmb = pm + (size_t)b * ATT_ * T_ + t0;
    const float* qb  = qbuf + b * ATT_;
#pragma unroll 2
    for (int a = 0; a < ATT_; ++a) {
        float q   = qb[a];
        float wsa = wsc[a];
        const float4* w1a4 = (const float4*)(w1 + a * LOC_);
        float pmv = pmb[(size_t)a * T_];
        float l2a = 0.f, l2b = 0.f;   // two chains to halve dependent latency
#pragma unroll
        for (int lq = 0; lq < 8; lq += 2) {
            float4 wv0 = w1a4[lq];
            float4 wv1 = w1a4[lq + 1];
            l2a = fmaf(wv0.x, loc[4 * lq + 0], l2a);
            l2b = fmaf(wv1.x, loc[4 * lq + 4], l2b);
            l2a = fmaf(wv0.y, loc[4 * lq + 1], l2a);
            l2b = fmaf(wv1.y, loc[4 * lq + 5], l2b);
            l2a = fmaf(wv0.z, loc[4 * lq + 2], l2a);
            l2b = fmaf(wv1.z, loc[4 * lq + 6], l2b);
            l2a = fmaf(wv0.w, loc[4 * lq + 3], l2a);
            l2b = fmaf(wv1.w, loc[4 * lq + 7], l2b);
        }
        score += wsa * fast_tanh(q + pmv + l2a + l2b);
    }

    unsigned char m = masks[(size_t)b * T_ + t0];
    float s = m ? -3.0e38f : score;
    pout[(size_t)b * T_ + t0] = fast_sigmoid(s);
}

// ---------------- Kernel C: alignments = prev*p + shift(prev*(1-p)) --------------
__global__ __launch_bounds__(256) void k_align(const float* __restrict__ p,
                                               const float* __restrict__ prev,
                                               float* __restrict__ align) {
    int idx = blockIdx.x * blockDim.x + threadIdx.x;
    int b  = idx / (T_ / 4);
    int t0 = (idx % (T_ / 4)) * 4;
    const float* pr = p + (size_t)b * T_;
    const float* vr = prev + (size_t)b * T_;
    float4 p4 = *(const float4*)(pr + t0);
    float4 v4 = *(const float4*)(vr + t0);
    float pm1 = (t0 > 0) ? pr[t0 - 1] : 0.f;
    float vm1 = (t0 > 0) ? vr[t0 - 1] : 0.f;
    float4 o;
    o.x = v4.x * p4.x + vm1 * (1.f - pm1);
    o.y = v4.y * p4.y + v4.x * (1.f - p4.x);
    o.z = v4.z * p4.z + v4.y * (1.f - p4.y);
    o.w = v4.w * p4.w + v4.z * (1.f - p4.z);
    *(float4*)(align + (size_t)b * T_ + t0) = o;
}

// ---------------- Kernel D: contexts[b,c] = sum_t align[b,t]*mem[b,c,t] ----------
// R3 best variant: one wave per (b,c) row, unroll 8, dual accumulators.
__global__ __launch_bounds__(256) void k_context(const float* __restrict__ mem,
                                                 const float* __restrict__ align,
                                                 float* __restrict__ ctx) {
    int w    = blockIdx.x * 4 + (threadIdx.x >> 6);
    int lane = threadIdx.x & 63;
    int b = w >> 9;   // /512
    int c = w & 511;
    const float4* mrow = (const float4*)(mem + ((size_t)b * ENC_ + c) * T_);
    const float4* arow = (const float4*)(align + (size_t)b * T_);
    float acc0 = 0.f, acc1 = 0.f;
#pragma unroll 8
    for (int i = 0; i < T_ / 256; ++i) {  // 32 iters, 16B/lane each
        float4 m = mrow[i * 64 + lane];
        float4 a = arow[i * 64 + lane];
        if (i & 1)
            acc1 += m.x * a.x + m.y * a.y + m.z * a.z + m.w * a.w;
        else
            acc0 += m.x * a.x + m.y * a.y + m.z * a.z + m.w * a.w;
    }
    float acc = acc0 + acc1;
#pragma unroll
    for (int off = 32; off; off >>= 1) acc += __shfl_xor(acc, off);
    if (lane == 0) ctx[b * ENC_ + c] = acc;
}

extern "C" void kernel_launch(void* const* d_in, const int* in_sizes, int n_in,
                              void* d_out, int out_size, void* d_ws, size_t ws_size,
                              hipStream_t stream) {
    const float* queries = (const float*)d_in[0];
    const float* memories = (const float*)d_in[1];
    const float* pm = (const float*)d_in[2];
    const float* prev = (const float*)d_in[3];
    const float* cum = (const float*)d_in[4];
    const unsigned char* masks = (const unsigned char*)d_in[5];
    const float* w_query = (const float*)d_in[6];
    const float* w_conv = (const float*)d_in[7];
    const float* w_1x1 = (const float*)d_in[8];
    const float* w_score = (const float*)d_in[9];

    float* out_ctx = (float*)d_out;                       // [B,ENC]
    float* out_align = (float*)d_out + (size_t)B_ * ENC_; // [B,T]

    float* ws_q = (float*)d_ws;                       // B*ATT
    float* ws_p = ws_q + B_ * ATT_;                   // B*T
    float* ws_wT = ws_p + (size_t)B_ * T_;            // K*2*LOC

    hipLaunchKernelGGL(k_prep_query, dim3((B_ * ATT_) / 4 + 1), dim3(256), 0, stream,
                       queries, w_query, w_conv, ws_q, ws_wT);
    hipLaunchKernelGGL(k_score, dim3(B_ * (T_ / TILE2)), dim3(BLK2), 0, stream,
                       pm, prev, cum, masks, ws_q, ws_wT, w_1x1, w_score, ws_p);
    hipLaunchKernelGGL(k_align, dim3((B_ * T_ / 4) / 256), dim3(256), 0, stream,
                       ws_p, prev, out_align);
    hipLaunchKernelGGL(k_context, dim3((B_ * ENC_) / 4), dim3(256), 0, stream,
                       memories, out_align, out_ctx);
}